// Round 1
// baseline (147.808 us; speedup 1.0000x reference)
//
#include <hip/hip_runtime.h>
#include <cstdint>

// Poincare-ball MLR:  out[row][n] = S_n * asinh( lam_row * inner[row][n] * A_n - (lam_row-1) * B_n )
//   inner = X @ Z  (bf16 MFMA),  lam_row = 2/(1 - ||x_row||^2)  (fp32, exact x)
//   A_n = cosh(2 r_n)/znorm_n,  B_n = sinh(2 r_n),  S_n = 2 znorm_n   (c = 1)

typedef __attribute__((ext_vector_type(8))) short short8;   // 8 bf16 = 4 VGPRs (MFMA A/B frag)
typedef __attribute__((ext_vector_type(4))) float floatx4;  // MFMA C/D frag

#define D 128
#define ZT_STRIDE 136   // +8 bf16 pad: row shift = 4 banks -> <=2-way LDS conflict (free)
#define TILE_M 128

__device__ inline unsigned bf16_rne(float f) {
    unsigned u = __float_as_uint(f);
    return ((u + 0x7FFFu + ((u >> 16) & 1u)) >> 16) & 0xFFFFu;
}

// ---------------- prep: Z column norms + transposed bf16 Z + per-col constants --------------
// grid 128 (one block per output column n), 128 threads (one per k)
__global__ void hmlr_prep(const float* __restrict__ z, const float* __restrict__ r,
                          unsigned short* __restrict__ zt, float* __restrict__ An,
                          float* __restrict__ Bn, float* __restrict__ Sn) {
    int n = blockIdx.x;
    int k = threadIdx.x;
    float v = z[k * D + n];                 // column n of Z
    zt[n * ZT_STRIDE + k] = (unsigned short)bf16_rne(v);  // Zt[n][k], k innermost
    float p = v * v;
    #pragma unroll
    for (int off = 32; off >= 1; off >>= 1) p += __shfl_down(p, off, 64);
    __shared__ float tmp[2];
    if ((k & 63) == 0) tmp[k >> 6] = p;
    __syncthreads();
    if (k == 0) {
        float ss = tmp[0] + tmp[1];
        float zn = fmaxf(sqrtf(ss), 1e-15f);
        float tc = 2.0f * r[n];             // 2*sqrt(c)*r, c=1
        An[n] = coshf(tc) / zn;
        Bn[n] = sinhf(tc);
        Sn[n] = 2.0f * zn;
    }
}

// ---------------- main: 1024 blocks x 256 threads, 128-row tile ----------------
__global__ __launch_bounds__(256) void hmlr_main(const float* __restrict__ x,
                                                 const unsigned short* __restrict__ zt,
                                                 const float* __restrict__ An,
                                                 const float* __restrict__ Bn,
                                                 const float* __restrict__ Sn,
                                                 float* __restrict__ out) {
    __shared__ __align__(16) unsigned short Xlds[TILE_M * ZT_STRIDE];  // bf16 X tile
    __shared__ float rowss[TILE_M];                                    // fp32 ||x||^2 per row

    const int t    = threadIdx.x;
    const int w    = t >> 6;         // wave 0..3
    const int l    = t & 63;
    const int quad = l >> 4;         // 0..3
    const int l15  = l & 15;

    const int row0 = blockIdx.x * TILE_M;
    const float4* xv = reinterpret_cast<const float4*>(x) + (size_t)blockIdx.x * (TILE_M * D / 4);

    // ---- stage X: fp32 global -> bf16 LDS, plus per-row sum-of-squares (fp32, pre-cast) ----
    #pragma unroll
    for (int i = 0; i < 16; ++i) {
        int f4  = t + 256 * i;                 // float4 index within tile
        float4 v = xv[f4];
        int row = f4 >> 5;                     // 32 float4s per row
        int k4  = (f4 & 31) << 2;
        float ssq = v.x * v.x + v.y * v.y + v.z * v.z + v.w * v.w;
        // the 32 contiguous lanes sharing this row reduce together; one lane owns the write
        ssq += __shfl_xor(ssq, 1);
        ssq += __shfl_xor(ssq, 2);
        ssq += __shfl_xor(ssq, 4);
        ssq += __shfl_xor(ssq, 8);
        ssq += __shfl_xor(ssq, 16);
        if ((t & 31) == 0) rowss[row] = ssq;
        unsigned lo = bf16_rne(v.x) | (bf16_rne(v.y) << 16);
        unsigned hi = bf16_rne(v.z) | (bf16_rne(v.w) << 16);
        *reinterpret_cast<uint2*>(&Xlds[row * ZT_STRIDE + k4]) = make_uint2(lo, hi);
    }
    __syncthreads();

    // ---- MFMA 16x16x32 bf16: wave w owns rows [32w, 32w+32), all 128 cols ----
    floatx4 acc[2][8];
    #pragma unroll
    for (int mt = 0; mt < 2; ++mt)
        #pragma unroll
        for (int nt = 0; nt < 8; ++nt)
            acc[mt][nt] = (floatx4){0.f, 0.f, 0.f, 0.f};

    #pragma unroll
    for (int kc = 0; kc < 4; ++kc) {
        const int kof = kc * 32 + quad * 8;
        // A frags: A[m = lane&15][k = quad*8 + j]  (contiguous 16B in LDS)
        short8 a0 = *reinterpret_cast<const short8*>(&Xlds[(w * 32 + l15) * ZT_STRIDE + kof]);
        short8 a1 = *reinterpret_cast<const short8*>(&Xlds[(w * 32 + 16 + l15) * ZT_STRIDE + kof]);
        #pragma unroll
        for (int nt = 0; nt < 8; ++nt) {
            // B frags: B[k = quad*8 + j][n = lane&15] read from k-innermost Zt (L1/L2-hot)
            short8 b = *reinterpret_cast<const short8*>(zt + (nt * 16 + l15) * ZT_STRIDE + kof);
            acc[0][nt] = __builtin_amdgcn_mfma_f32_16x16x32_bf16(a0, b, acc[0][nt], 0, 0, 0);
            acc[1][nt] = __builtin_amdgcn_mfma_f32_16x16x32_bf16(a1, b, acc[1][nt], 0, 0, 0);
        }
    }

    // ---- epilogue: C/D layout col = lane&15, row = quad*4 + reg ----
    float anv[8], bnv[8], snv[8];
    #pragma unroll
    for (int nt = 0; nt < 8; ++nt) {
        int n = nt * 16 + l15;
        anv[nt] = An[n];
        bnv[nt] = Bn[n];
        snv[nt] = Sn[n];
    }
    #pragma unroll
    for (int mt = 0; mt < 2; ++mt) {
        #pragma unroll
        for (int reg = 0; reg < 4; ++reg) {
            int rlocal = w * 32 + mt * 16 + quad * 4 + reg;
            float lam  = 2.0f / (1.0f - rowss[rlocal]);
            float lm1  = lam - 1.0f;
            float* orow = out + (size_t)(row0 + rlocal) * D + l15;
            #pragma unroll
            for (int nt = 0; nt < 8; ++nt) {
                float inner = acc[mt][nt][reg];
                float arg = __fmaf_rn(lam * inner, anv[nt], -lm1 * bnv[nt]);
                float a  = fabsf(arg);
                float as = __logf(a + __fsqrt_rn(__fmaf_rn(a, a, 1.0f)));  // asinh(|arg|)
                orow[nt * 16] = copysignf(as, arg) * snv[nt];
            }
        }
    }
}

extern "C" void kernel_launch(void* const* d_in, const int* in_sizes, int n_in,
                              void* d_out, int out_size, void* d_ws, size_t ws_size,
                              hipStream_t stream) {
    const float* x = (const float*)d_in[0];   // [16*8192, 128] fp32
    const float* z = (const float*)d_in[1];   // [128, 128] fp32
    const float* r = (const float*)d_in[2];   // [128] fp32
    float* out = (float*)d_out;

    // ws layout: Zt bf16 [128][136] (34816 B) | An[128] | Bn[128] | Sn[128]
    char* wsb = (char*)d_ws;
    unsigned short* zt = (unsigned short*)wsb;
    float* An = (float*)(wsb + 128 * ZT_STRIDE * sizeof(unsigned short));
    float* Bn = An + 128;
    float* Sn = An + 256;

    hmlr_prep<<<128, 128, 0, stream>>>(z, r, zt, An, Bn, Sn);

    const int n_rows = in_sizes[0] / D;       // 131072
    hmlr_main<<<n_rows / TILE_M, 256, 0, stream>>>(x, zt, An, Bn, Sn, out);
}

// Round 2
// 140.279 us; speedup vs baseline: 1.0537x; 1.0537x over previous
//
#include <hip/hip_runtime.h>
#include <cstdint>

// Poincare-ball MLR:  out[row][n] = S_n * asinh( lam_row * inner[row][n] * A_n - (lam_row-1) * B_n )
//   inner = X @ Z  (bf16 MFMA),  lam_row = 2/(1 - ||x_row||^2)  (fp32, exact x)
//   A_n = cosh(2 r_n)/znorm_n,  B_n = sinh(2 r_n),  S_n = 2 znorm_n   (c = 1)
//
// R2: barrier-free, LDS-free main kernel. Each wave owns 16 rows end-to-end:
// A-frags loaded directly from global in MFMA A-layout, ||x||^2 via 2 shfl_xor,
// B-frags from L1/L2-hot transposed-bf16 Zt. 2048 blocks x 4 independent waves.

typedef __attribute__((ext_vector_type(8))) short short8;   // 8 bf16 = 4 VGPRs (MFMA A/B frag)
typedef __attribute__((ext_vector_type(4))) float floatx4;  // MFMA C/D frag

#define D 128
#define ZT_STRIDE 136   // bf16 elems; 272 B row pitch (16B-aligned rows)

__device__ inline unsigned bf16_rne(float f) {
    unsigned u = __float_as_uint(f);
    return ((u + 0x7FFFu + ((u >> 16) & 1u)) >> 16) & 0xFFFFu;
}

// ---------------- prep: Z column norms + transposed bf16 Z + per-col constants --------------
// grid 128 (one block per output column n), 128 threads (one per k)
__global__ void hmlr_prep(const float* __restrict__ z, const float* __restrict__ r,
                          unsigned short* __restrict__ zt, float* __restrict__ An,
                          float* __restrict__ Bn, float* __restrict__ Sn) {
    int n = blockIdx.x;
    int k = threadIdx.x;
    float v = z[k * D + n];                 // column n of Z
    zt[n * ZT_STRIDE + k] = (unsigned short)bf16_rne(v);  // Zt[n][k], k innermost
    float p = v * v;
    #pragma unroll
    for (int off = 32; off >= 1; off >>= 1) p += __shfl_down(p, off, 64);
    __shared__ float tmp[2];
    if ((k & 63) == 0) tmp[k >> 6] = p;
    __syncthreads();
    if (k == 0) {
        float ss = tmp[0] + tmp[1];
        float zn = fmaxf(sqrtf(ss), 1e-15f);
        float tc = 2.0f * r[n];             // 2*sqrt(c)*r, c=1
        An[n] = coshf(tc) / zn;
        Bn[n] = sinhf(tc);
        Sn[n] = 2.0f * zn;
    }
}

// ---------------- main: wave-independent, 16 rows/wave, no LDS, no barriers ----------------
__global__ __launch_bounds__(256) void hmlr_main(const float* __restrict__ x,
                                                 const unsigned short* __restrict__ zt,
                                                 const float* __restrict__ An,
                                                 const float* __restrict__ Bn,
                                                 const float* __restrict__ Sn,
                                                 float* __restrict__ out) {
    const int t    = threadIdx.x;
    const int w    = t >> 6;         // wave 0..3
    const int l    = t & 63;
    const int quad = l >> 4;         // 0..3
    const int l15  = l & 15;

    const int rowbase = blockIdx.x * 64 + w * 16;   // this wave's 16 rows
    const int myrow   = rowbase + l15;

    // ---- A loads in MFMA A-layout: lane = row l15, k = kc*32 + quad*8 + j (8 contiguous) ----
    const float* xrow = x + (size_t)myrow * D + quad * 8;
    float4 xv[8];
    #pragma unroll
    for (int kc = 0; kc < 4; ++kc) {
        xv[2 * kc]     = *reinterpret_cast<const float4*>(xrow + kc * 32);
        xv[2 * kc + 1] = *reinterpret_cast<const float4*>(xrow + kc * 32 + 4);
    }

    // ---- ||x_row||^2 in fp32 (pre-cast): partial over this lane's 32 elems, then
    //      combine the 4 quads that share l15 (lane bits 4,5) ----
    float ssq = 0.f;
    #pragma unroll
    for (int i = 0; i < 8; ++i)
        ssq += xv[i].x * xv[i].x + xv[i].y * xv[i].y + xv[i].z * xv[i].z + xv[i].w * xv[i].w;
    ssq += __shfl_xor(ssq, 16);
    ssq += __shfl_xor(ssq, 32);      // every lane now holds ||x||^2 of row (rowbase + l15)

    // ---- convert to bf16 A-frags ----
    short8 afrag[4];
    #pragma unroll
    for (int kc = 0; kc < 4; ++kc) {
        float4 v0 = xv[2 * kc], v1 = xv[2 * kc + 1];
        union { short8 s8; unsigned short u[8]; } af;
        af.u[0] = (unsigned short)bf16_rne(v0.x);
        af.u[1] = (unsigned short)bf16_rne(v0.y);
        af.u[2] = (unsigned short)bf16_rne(v0.z);
        af.u[3] = (unsigned short)bf16_rne(v0.w);
        af.u[4] = (unsigned short)bf16_rne(v1.x);
        af.u[5] = (unsigned short)bf16_rne(v1.y);
        af.u[6] = (unsigned short)bf16_rne(v1.z);
        af.u[7] = (unsigned short)bf16_rne(v1.w);
        afrag[kc] = af.s8;
    }

    // ---- MFMA 16x16x32 bf16 over all 8 n-tiles; B frags from L1/L2-hot Zt ----
    floatx4 acc[8];
    #pragma unroll
    for (int nt = 0; nt < 8; ++nt) acc[nt] = (floatx4){0.f, 0.f, 0.f, 0.f};

    #pragma unroll
    for (int kc = 0; kc < 4; ++kc) {
        const unsigned short* zb = zt + kc * 32 + quad * 8;
        #pragma unroll
        for (int nt = 0; nt < 8; ++nt) {
            short8 b = *reinterpret_cast<const short8*>(zb + (nt * 16 + l15) * ZT_STRIDE);
            acc[nt] = __builtin_amdgcn_mfma_f32_16x16x32_bf16(afrag[kc], b, acc[nt], 0, 0, 0);
        }
    }

    // ---- epilogue: C/D layout col = lane&15, row = quad*4 + reg ----
    float anv[8], bnv[8], snv[8];
    #pragma unroll
    for (int nt = 0; nt < 8; ++nt) {
        int n = nt * 16 + l15;
        anv[nt] = An[n];
        bnv[nt] = Bn[n];
        snv[nt] = Sn[n];
    }
    #pragma unroll
    for (int reg = 0; reg < 4; ++reg) {
        float rss = __shfl(ssq, quad * 4 + reg);          // row (quad*4+reg)'s ||x||^2
        float lam = 2.0f / (1.0f - rss);
        float lm1 = lam - 1.0f;
        float* orow = out + (size_t)(rowbase + quad * 4 + reg) * D + l15;
        #pragma unroll
        for (int nt = 0; nt < 8; ++nt) {
            float inner = acc[nt][reg];
            float arg = __fmaf_rn(lam * inner, anv[nt], -lm1 * bnv[nt]);
            float a   = fabsf(arg);
            float as  = __logf(a + __fsqrt_rn(__fmaf_rn(a, a, 1.0f)));  // asinh(|arg|)
            orow[nt * 16] = copysignf(as, arg) * snv[nt];
        }
    }
}

extern "C" void kernel_launch(void* const* d_in, const int* in_sizes, int n_in,
                              void* d_out, int out_size, void* d_ws, size_t ws_size,
                              hipStream_t stream) {
    const float* x = (const float*)d_in[0];   // [16*8192, 128] fp32
    const float* z = (const float*)d_in[1];   // [128, 128] fp32
    const float* r = (const float*)d_in[2];   // [128] fp32
    float* out = (float*)d_out;

    // ws layout: Zt bf16 [128][136] (34816 B) | An[128] | Bn[128] | Sn[128]
    char* wsb = (char*)d_ws;
    unsigned short* zt = (unsigned short*)wsb;
    float* An = (float*)(wsb + 128 * ZT_STRIDE * sizeof(unsigned short));
    float* Bn = An + 128;
    float* Sn = An + 256;

    hmlr_prep<<<128, 128, 0, stream>>>(z, r, zt, An, Bn, Sn);

    const int n_rows = in_sizes[0] / D;       // 131072
    hmlr_main<<<n_rows / 64, 256, 0, stream>>>(x, zt, An, Bn, Sn, out);
}

// Round 3
// 125.376 us; speedup vs baseline: 1.1789x; 1.1189x over previous
//
#include <hip/hip_runtime.h>
#include <cstdint>

// Poincare-ball MLR:  out[row][n] = S_n * asinh( lam_row * inner[row][n] * A_n - (lam_row-1) * B_n )
//   inner = X @ Z  (bf16 MFMA),  lam_row = 2/(1 - ||x_row||^2)  (fp32, exact x)
//   A_n = cosh(2 r_n)/znorm_n,  B_n = sinh(2 r_n),  S_n = 2 znorm_n   (c = 1)
//
// R3: kill the TA-bound gathers of R2. All MFMA fragments come from LDS
// (XOR-swizzled 16B chunks, structural-minimum bank usage); X is loaded with
// fully-coalesced 1KB float4 reads into a wave-private LDS region (no barrier);
// Zt is staged once per block behind the single __syncthreads. ||x||^2 reaches
// the epilogue via a register transpose (7 cndmask + 1 shfl_xor). 512-thr
// blocks, 64KB LDS -> 2 blocks/CU, 16 waves/CU.

typedef __attribute__((ext_vector_type(8))) short short8;   // 8 bf16 = 4 VGPRs (MFMA A/B frag)
typedef __attribute__((ext_vector_type(4))) float floatx4;  // MFMA C/D frag

#define D 128

__device__ inline unsigned bf16_rne(float f) {
    unsigned u = __float_as_uint(f);
    return ((u + 0x7FFFu + ((u >> 16) & 1u)) >> 16) & 0xFFFFu;
}

// ---------------- prep: compact bf16 Zt + packed per-col constants {A,B,S,0} ----------------
// grid 128 (one block per output column n), 128 threads (one per k)
__global__ void hmlr_prep(const float* __restrict__ z, const float* __restrict__ r,
                          unsigned short* __restrict__ zt, float4* __restrict__ abs4) {
    int n = blockIdx.x;
    int k = threadIdx.x;
    float v = z[k * D + n];                          // column n of Z
    zt[n * D + k] = (unsigned short)bf16_rne(v);     // Zt[n][k] compact, k innermost
    float p = v * v;
    #pragma unroll
    for (int off = 32; off >= 1; off >>= 1) p += __shfl_down(p, off, 64);
    __shared__ float tmp[2];
    if ((k & 63) == 0) tmp[k >> 6] = p;
    __syncthreads();
    if (k == 0) {
        float ss = tmp[0] + tmp[1];
        float zn = fmaxf(sqrtf(ss), 1e-15f);
        float tc = 2.0f * r[n];                      // 2*sqrt(c)*r, c=1
        abs4[n] = make_float4(coshf(tc) / zn, sinhf(tc), 2.0f * zn, 0.0f);
    }
}

// ---------------- main: 1024 blocks x 512 threads, 8 waves x 16 rows = 128 rows/block -------
__global__ __launch_bounds__(512, 4) void hmlr_main(const float* __restrict__ x,
                                                    const unsigned short* __restrict__ zt,
                                                    const float4* __restrict__ abs4,
                                                    float* __restrict__ out) {
    // LDS: [0, 32768) = X tile bf16 (128 rows x 256B, XOR-swizzled 16B chunks)
    //      [32768, 65536) = Zt bf16 (128 rows x 256B, same swizzle)
    __shared__ __align__(16) unsigned char lds[65536];
    #define LDS_Z 32768

    const int t    = threadIdx.x;
    const int w    = t >> 6;         // wave 0..7
    const int l    = t & 63;
    const int quad = l >> 4;         // 0..3
    const int l15  = l & 15;
    const int l7   = l15 & 7;

    const int rowbase = blockIdx.x * 128 + w * 16;   // this wave's 16 rows

    // ---- Zt slice loads (1/8 per wave, coalesced 16B chunks), kept in regs for now ----
    const uint4* ztg = reinterpret_cast<const uint4*>(zt);
    uint4 zreg[4];
    #pragma unroll
    for (int i = 0; i < 4; ++i) zreg[i] = ztg[t + (i << 9)];   // chunk idx t + 512*i

    // ---- X loads: wave-private, fully coalesced 1KB per inst ----
    const float4* xg = reinterpret_cast<const float4*>(x) + (size_t)blockIdx.x * 4096 + w * 512;
    float4 xv[8];
    #pragma unroll
    for (int j = 0; j < 8; ++j) xv[j] = xg[(j << 6) + l];

    // ---- process X: ssq partials + bf16 pack + swizzled LDS write (wave-private region) ----
    float s[8];
    #pragma unroll
    for (int j = 0; j < 8; ++j) {
        float4 v = xv[j];
        int f   = (j << 6) + l;          // f4 index within wave's 512
        int row = w * 16 + (f >> 5);     // LDS row (block-local)
        int fc  = f & 31;
        float p = v.x * v.x + v.y * v.y + v.z * v.z + v.w * v.w;
        p += __shfl_xor(p, 1);
        p += __shfl_xor(p, 2);
        p += __shfl_xor(p, 4);
        p += __shfl_xor(p, 8);
        p += __shfl_xor(p, 16);
        s[j] = p;                        // full ssq of row (16w + 2j + (l>>5))
        unsigned lo = bf16_rne(v.x) | (bf16_rne(v.y) << 16);
        unsigned hi = bf16_rne(v.z) | (bf16_rne(v.w) << 16);
        int byte = (row << 8) + ((((fc >> 1) ^ (row & 7)) << 4)) + ((fc & 1) << 3);
        *reinterpret_cast<uint2*>(&lds[byte]) = make_uint2(lo, hi);
    }

    // ---- register transpose: rq = ssq of row (16w + (l&15)) ----
    int idx3 = (l >> 1) & 7;
    float a0 = (idx3 & 1) ? s[1] : s[0];
    float a1 = (idx3 & 1) ? s[3] : s[2];
    float a2 = (idx3 & 1) ? s[5] : s[4];
    float a3 = (idx3 & 1) ? s[7] : s[6];
    float b0 = (idx3 & 2) ? a1 : a0;
    float b1 = (idx3 & 2) ? a3 : a2;
    float vsel = (idx3 & 4) ? b1 : b0;
    float usel = __shfl_xor(vsel, 32);
    float rq = (((l >> 5) & 1) == (l & 1)) ? vsel : usel;

    // ---- A-frags from wave-private LDS (no barrier needed) ----
    short8 afrag[4];
    #pragma unroll
    for (int kc = 0; kc < 4; ++kc) {
        int byte = ((w * 16 + l15) << 8) + (((quad + (kc << 2)) ^ l7) << 4);
        afrag[kc] = *reinterpret_cast<const short8*>(&lds[byte]);
    }

    // ---- Zt slice into LDS, then the block's only barrier ----
    #pragma unroll
    for (int i = 0; i < 4; ++i) {
        int idx = t + (i << 9);          // 16B chunk 0..2047
        int row = idx >> 4, c = idx & 15;
        int byte = LDS_Z + (row << 8) + (((c ^ (row & 7)) << 4));
        *reinterpret_cast<uint4*>(&lds[byte]) = zreg[i];
    }
    __syncthreads();

    // ---- per-col constants in flight (L2-hot, 4-way broadcast per inst) ----
    float4 cst[8];
    #pragma unroll
    for (int nt = 0; nt < 8; ++nt) cst[nt] = abs4[nt * 16 + l15];

    // ---- MFMA 16x16x32 bf16: B-frags from LDS ----
    floatx4 acc[8];
    #pragma unroll
    for (int nt = 0; nt < 8; ++nt) acc[nt] = (floatx4){0.f, 0.f, 0.f, 0.f};

    #pragma unroll
    for (int kc = 0; kc < 4; ++kc) {
        #pragma unroll
        for (int nt = 0; nt < 8; ++nt) {
            int byte = LDS_Z + ((nt * 16 + l15) << 8) + (((quad + (kc << 2)) ^ l7) << 4);
            short8 b = *reinterpret_cast<const short8*>(&lds[byte]);
            acc[nt] = __builtin_amdgcn_mfma_f32_16x16x32_bf16(afrag[kc], b, acc[nt], 0, 0, 0);
        }
    }

    // ---- epilogue: C/D layout col = lane&15, row = quad*4 + reg ----
    #pragma unroll
    for (int reg = 0; reg < 4; ++reg) {
        float rss = __shfl(rq, (quad << 2) | reg);    // ssq of row quad*4+reg
        float lam = 2.0f / (1.0f - rss);
        float lm1 = lam - 1.0f;
        float* orow = out + (size_t)(rowbase + (quad << 2) + reg) * D + l15;
        #pragma unroll
        for (int nt = 0; nt < 8; ++nt) {
            float inner = acc[nt][reg];
            float arg = __fmaf_rn(lam * inner, cst[nt].x, -lm1 * cst[nt].y);
            float a   = fabsf(arg);
            float as  = __logf(a + __fsqrt_rn(__fmaf_rn(a, a, 1.0f)));  // asinh(|arg|)
            orow[nt * 16] = copysignf(as, arg) * cst[nt].z;
        }
    }
    #undef LDS_Z
}

extern "C" void kernel_launch(void* const* d_in, const int* in_sizes, int n_in,
                              void* d_out, int out_size, void* d_ws, size_t ws_size,
                              hipStream_t stream) {
    const float* x = (const float*)d_in[0];   // [16*8192, 128] fp32
    const float* z = (const float*)d_in[1];   // [128, 128] fp32
    const float* r = (const float*)d_in[2];   // [128] fp32
    float* out = (float*)d_out;

    // ws layout: Zt bf16 compact [128][128] (32768 B) | abs4 float4[128] (2048 B)
    char* wsb = (char*)d_ws;
    unsigned short* zt = (unsigned short*)wsb;
    float4* abs4 = (float4*)(wsb + 128 * D * sizeof(unsigned short));

    hmlr_prep<<<128, 128, 0, stream>>>(z, r, zt, abs4);

    const int n_rows = in_sizes[0] / D;       // 131072
    hmlr_main<<<n_rows / 128, 512, 0, stream>>>(x, zt, abs4, out);
}

// Round 4
// 123.968 us; speedup vs baseline: 1.1923x; 1.0114x over previous
//
#include <hip/hip_runtime.h>
#include <cstdint>

// Poincare-ball MLR:  out[row][n] = S_n * asinh( lam_row * inner[row][n] * A_n - (lam_row-1) * B_n )
//   inner = X @ Z  (bf16 MFMA),  lam_row = 2/(1 - ||x_row||^2)
//   A_n = cosh(2 r_n)/znorm_n,  B_n = sinh(2 r_n),  S_n = 2 znorm_n   (c = 1)
//
// R4: epilogue de-scattered. inner staged through wave-private LDS (2 passes x 4KB,
// reusing the dead X region), read back linearly, asinh computed in transposed
// layout (each lane owns 4 contiguous cols -> constants are 3 coalesced float4
// loads), stores are 8 x 1KB global_store_dwordx4. ||x||^2 comes from an extra
// MFMA chain D = Xtile * Xtile^T (diagonal = row norms; symmetric so layout-proof),
// replacing 40 ds_bpermute shuffles.

typedef __attribute__((ext_vector_type(8))) short short8;   // 8 bf16 = 4 VGPRs (MFMA A/B frag)
typedef __attribute__((ext_vector_type(4))) float floatx4;  // MFMA C/D frag

#define D 128

__device__ inline unsigned bf16_rne(float f) {
    unsigned u = __float_as_uint(f);
    return ((u + 0x7FFFu + ((u >> 16) & 1u)) >> 16) & 0xFFFFu;
}

// ---------------- prep: compact bf16 Zt + per-col constant arrays An/Bn/Sn ----------------
// grid 128 (one block per output column n), 128 threads (one per k)
__global__ void hmlr_prep(const float* __restrict__ z, const float* __restrict__ r,
                          unsigned short* __restrict__ zt, float* __restrict__ An,
                          float* __restrict__ Bn, float* __restrict__ Sn) {
    int n = blockIdx.x;
    int k = threadIdx.x;
    float v = z[k * D + n];                          // column n of Z
    zt[n * D + k] = (unsigned short)bf16_rne(v);     // Zt[n][k] compact, k innermost
    float p = v * v;
    #pragma unroll
    for (int off = 32; off >= 1; off >>= 1) p += __shfl_down(p, off, 64);
    __shared__ float tmp[2];
    if ((k & 63) == 0) tmp[k >> 6] = p;
    __syncthreads();
    if (k == 0) {
        float ss = tmp[0] + tmp[1];
        float zn = fmaxf(sqrtf(ss), 1e-15f);
        float tc = 2.0f * r[n];                      // 2*sqrt(c)*r, c=1
        An[n] = coshf(tc) / zn;
        Bn[n] = sinhf(tc);
        Sn[n] = 2.0f * zn;
    }
}

// ---------------- main: 1024 blocks x 512 threads, 8 waves x 16 rows = 128 rows/block -------
__global__ __launch_bounds__(512, 4) void hmlr_main(const float* __restrict__ x,
                                                    const unsigned short* __restrict__ zt,
                                                    const float* __restrict__ An,
                                                    const float* __restrict__ Bn,
                                                    const float* __restrict__ Sn,
                                                    float* __restrict__ out) {
    // LDS: [0, 32768) = X tile bf16 (128 rows x 256B, XOR-swizzled 16B chunks);
    //                   per-wave 4KB slice reused later to stage the fp32 inner tile
    //      [32768, 65536) = Zt bf16 (128 rows x 256B, same swizzle)
    __shared__ __align__(16) unsigned char lds[65536];
    #define LDS_Z 32768

    const int t    = threadIdx.x;
    const int w    = t >> 6;         // wave 0..7
    const int l    = t & 63;
    const int quad = l >> 4;         // 0..3
    const int l15  = l & 15;
    const int l7   = l15 & 7;

    const int rowbase = blockIdx.x * 128 + w * 16;   // this wave's 16 rows

    // ---- Zt slice loads (1/8 per wave, coalesced 16B chunks), kept in regs for now ----
    const uint4* ztg = reinterpret_cast<const uint4*>(zt);
    uint4 zreg[4];
    #pragma unroll
    for (int i = 0; i < 4; ++i) zreg[i] = ztg[t + (i << 9)];   // chunk idx t + 512*i

    // ---- X loads: wave-private, fully coalesced 1KB per inst ----
    const float4* xg = reinterpret_cast<const float4*>(x) + (size_t)blockIdx.x * 4096 + w * 512;
    float4 xv[8];
    #pragma unroll
    for (int j = 0; j < 8; ++j) xv[j] = xg[(j << 6) + l];

    // ---- pack bf16 + swizzled LDS write (wave-private region, no barrier) ----
    #pragma unroll
    for (int j = 0; j < 8; ++j) {
        float4 v = xv[j];
        int f   = (j << 6) + l;          // f4 index within wave's 512
        int row = w * 16 + (f >> 5);     // LDS row (block-local)
        int fc  = f & 31;
        unsigned lo = bf16_rne(v.x) | (bf16_rne(v.y) << 16);
        unsigned hi = bf16_rne(v.z) | (bf16_rne(v.w) << 16);
        int byte = (row << 8) + ((((fc >> 1) ^ (row & 7)) << 4)) + ((fc & 1) << 3);
        *reinterpret_cast<uint2*>(&lds[byte]) = make_uint2(lo, hi);
    }

    // ---- A-frags from wave-private LDS (same-wave ordering, no barrier) ----
    short8 afrag[4];
    #pragma unroll
    for (int kc = 0; kc < 4; ++kc) {
        int byte = ((w * 16 + l15) << 8) + (((quad + (kc << 2)) ^ l7) << 4);
        afrag[kc] = *reinterpret_cast<const short8*>(&lds[byte]);
    }

    // ---- Zt slice into LDS, then the block's only barrier ----
    #pragma unroll
    for (int i = 0; i < 4; ++i) {
        int idx = t + (i << 9);          // 16B chunk 0..2047
        int row = idx >> 4, c = idx & 15;
        int byte = LDS_Z + (row << 8) + (((c ^ (row & 7)) << 4));
        *reinterpret_cast<uint4*>(&lds[byte]) = zreg[i];
    }
    __syncthreads();

    // ---- per-lane constants for the transposed epilogue: 4 contiguous cols ----
    const int col0 = (l & 31) << 2;
    float4 A4 = *reinterpret_cast<const float4*>(An + col0);
    float4 B4 = *reinterpret_cast<const float4*>(Bn + col0);
    float4 S4 = *reinterpret_cast<const float4*>(Sn + col0);

    // ---- MFMA 16x16x32 bf16: inner = X@Z (B-frags from LDS) + D = X@X^T for row norms ----
    floatx4 acc[8];
    #pragma unroll
    for (int nt = 0; nt < 8; ++nt) acc[nt] = (floatx4){0.f, 0.f, 0.f, 0.f};
    floatx4 accd = (floatx4){0.f, 0.f, 0.f, 0.f};

    #pragma unroll
    for (int kc = 0; kc < 4; ++kc) {
        accd = __builtin_amdgcn_mfma_f32_16x16x32_bf16(afrag[kc], afrag[kc], accd, 0, 0, 0);
        #pragma unroll
        for (int nt = 0; nt < 8; ++nt) {
            int byte = LDS_Z + ((nt * 16 + l15) << 8) + (((quad + (kc << 2)) ^ l7) << 4);
            short8 b = *reinterpret_cast<const short8*>(&lds[byte]);
            acc[nt] = __builtin_amdgcn_mfma_f32_16x16x32_bf16(afrag[kc], b, acc[nt], 0, 0, 0);
        }
    }

    // diag of X@X^T: row r lives at lane (r>>2)*16 + r, reg r&3  ->  per-lane candidate
    float cand = accd[l15 & 3];

    // ---- transposed epilogue: 2 passes x (stage 8 rows fp32 -> linear readback) ----
    float4* outv = reinterpret_cast<float4*>(out + (size_t)rowbase * D);
    const int pbase = w << 12;           // wave's 4KB LDS slice (dead X region)

    #pragma unroll
    for (int pass = 0; pass < 2; ++pass) {
        if ((quad >> 1) == pass) {       // quads 2p,2p+1 hold rows 8p..8p+7
            int pr = (quad & 1) << 2;    // pass-local row base
            #pragma unroll
            for (int reg = 0; reg < 4; ++reg) {
                #pragma unroll
                for (int nt = 0; nt < 8; ++nt) {
                    int byte = pbase + ((pr + reg) << 9) + ((l15 + (nt << 4)) << 2);
                    *reinterpret_cast<float*>(&lds[byte]) = acc[nt][reg];
                }
            }
        }
        // same-wave DS ordering: reads below see the writes above without a barrier
        #pragma unroll
        for (int j = 0; j < 4; ++j) {
            int fi = (j << 6) + l;                           // float4 idx in the 4KB slice
            float4 v = *reinterpret_cast<const float4*>(&lds[pbase + (fi << 4)]);
            int rl = (pass << 3) + (fi >> 5);                // block-wave-local row 0..15
            float ssq = __shfl(cand, ((rl >> 2) << 4) + rl); // ||x_row||^2 from X@X^T diag
            float lam = 2.0f / (1.0f - ssq);
            float lm1 = lam - 1.0f;
            float4 res;
            {
                float arg = __fmaf_rn(lam * v.x, A4.x, -lm1 * B4.x);
                float a = fabsf(arg);
                res.x = copysignf(__logf(a + __fsqrt_rn(__fmaf_rn(a, a, 1.0f))), arg) * S4.x;
            }
            {
                float arg = __fmaf_rn(lam * v.y, A4.y, -lm1 * B4.y);
                float a = fabsf(arg);
                res.y = copysignf(__logf(a + __fsqrt_rn(__fmaf_rn(a, a, 1.0f))), arg) * S4.y;
            }
            {
                float arg = __fmaf_rn(lam * v.z, A4.z, -lm1 * B4.z);
                float a = fabsf(arg);
                res.z = copysignf(__logf(a + __fsqrt_rn(__fmaf_rn(a, a, 1.0f))), arg) * S4.z;
            }
            {
                float arg = __fmaf_rn(lam * v.w, A4.w, -lm1 * B4.w);
                float a = fabsf(arg);
                res.w = copysignf(__logf(a + __fsqrt_rn(__fmaf_rn(a, a, 1.0f))), arg) * S4.w;
            }
            outv[(pass << 8) + fi] = res;                    // 1KB coalesced store
        }
    }
    #undef LDS_Z
}

extern "C" void kernel_launch(void* const* d_in, const int* in_sizes, int n_in,
                              void* d_out, int out_size, void* d_ws, size_t ws_size,
                              hipStream_t stream) {
    const float* x = (const float*)d_in[0];   // [16*8192, 128] fp32
    const float* z = (const float*)d_in[1];   // [128, 128] fp32
    const float* r = (const float*)d_in[2];   // [128] fp32
    float* out = (float*)d_out;

    // ws layout: Zt bf16 compact [128][128] (32768 B) | An[128] | Bn[128] | Sn[128]
    char* wsb = (char*)d_ws;
    unsigned short* zt = (unsigned short*)wsb;
    float* An = (float*)(wsb + 128 * D * sizeof(unsigned short));
    float* Bn = An + 128;
    float* Sn = An + 256;

    hmlr_prep<<<128, 128, 0, stream>>>(z, r, zt, An, Bn, Sn);

    const int n_rows = in_sizes[0] / D;       // 131072
    hmlr_main<<<n_rows / 128, 512, 0, stream>>>(x, zt, An, Bn, Sn, out);
}

// Round 6
// 120.993 us; speedup vs baseline: 1.2216x; 1.0246x over previous
//
#include <hip/hip_runtime.h>
#include <cstdint>

// Poincare-ball MLR:  out[row][n] = S_n * asinh( lam_row * inner[row][n] * A_n - (lam_row-1) * B_n )
//   inner = X @ Z  (bf16 MFMA),  lam_row = 2/(1 - ||x_row||^2)
//   A_n = cosh(2 r_n)/znorm_n,  B_n = sinh(2 r_n),  S_n = 2 znorm_n   (c = 1)
//
// R5b: R5 with the compile fix (__sqrtf -> __fsqrt_rn).
// (1) epilogue = R2/R3-proven direct scatter stores;
// (2) X never touches LDS: A-frags gathered from global in MFMA A-layout,
//     ssq in fp32 via 2 shfl_xor, cheap bit-trick bf16 pack;
// (3) LDS = Zt only (32KB) staged by async global_load_lds width=16 from a
//     PRE-SWIZZLED ws copy -> 5 blocks/CU (20 waves/CU), barrier waits on
//     L2-hot Zt only; per-kc B-frag preload for ILP. launch_bounds(256,5).

typedef __attribute__((ext_vector_type(8))) short short8;   // 8 bf16 = 4 VGPRs (MFMA A/B frag)
typedef __attribute__((ext_vector_type(4))) float floatx4;  // MFMA C/D frag

#define D 128

__device__ inline unsigned bf16_rhu(float f) {   // round-half-up to bf16, bit trick (2 VALU)
    return (__float_as_uint(f) + 0x8000u) >> 16;
}
__device__ inline unsigned pack2(float lo, float hi) {
    return bf16_rhu(lo) | (bf16_rhu(hi) << 16);
}

// ---------------- prep: PRE-SWIZZLED bf16 Zt + packed per-col constants ----------------
// zt_sw chunk layout: 16B chunk (row, c) stored at chunk index row*16 + (c ^ (row&7)),
// so a linear global_load_lds stage reproduces the swizzled LDS layout.
// abs4[n] = { cosh(2r)/zn, sinh(2r), 2*zn*ln2, 0 }   (ln2 folded: asinh via log2)
__global__ void hmlr_prep(const float* __restrict__ z, const float* __restrict__ r,
                          unsigned short* __restrict__ zt_sw, float4* __restrict__ abs4) {
    int n = blockIdx.x;
    int k = threadIdx.x;
    float v = z[k * D + n];                          // column n of Z
    int c = k >> 3, p = k & 7;
    zt_sw[n * D + ((c ^ (n & 7)) << 3) + p] = (unsigned short)bf16_rhu(v);
    float pw = v * v;
    #pragma unroll
    for (int off = 32; off >= 1; off >>= 1) pw += __shfl_down(pw, off, 64);
    __shared__ float tmp[2];
    if ((k & 63) == 0) tmp[k >> 6] = pw;
    __syncthreads();
    if (k == 0) {
        float ss = tmp[0] + tmp[1];
        float zn = fmaxf(sqrtf(ss), 1e-15f);
        float tc = 2.0f * r[n];                      // 2*sqrt(c)*r, c=1
        abs4[n] = make_float4(coshf(tc) / zn, sinhf(tc),
                              2.0f * zn * 0.69314718055994531f, 0.0f);
    }
}

// ---------------- main: 2048 blocks x 256 threads, 4 waves x 16 rows = 64 rows/block ------
__global__ __launch_bounds__(256, 5) void hmlr_main(const float* __restrict__ x,
                                                    const unsigned short* __restrict__ zt_sw,
                                                    const float4* __restrict__ abs4,
                                                    float* __restrict__ out) {
    __shared__ __align__(16) unsigned char lds[32768];   // Zt bf16, swizzled 16B chunks

    const int t    = threadIdx.x;
    const int w    = t >> 6;         // wave 0..3
    const int l    = t & 63;
    const int quad = l >> 4;         // 0..3
    const int l15  = l & 15;
    const int l7   = l & 7;

    // ---- Zt -> LDS: async direct-to-LDS, 1KB per wave-instruction, 8 per wave ----
#if __has_builtin(__builtin_amdgcn_global_load_lds)
    #pragma unroll
    for (int i = 0; i < 8; ++i) {
        int ci = w * 512 + i * 64 + l;               // 16B chunk index 0..2047
        __builtin_amdgcn_global_load_lds(
            (const __attribute__((address_space(1))) unsigned int*)(zt_sw + (ci << 3)),
            (__attribute__((address_space(3))) unsigned int*)(lds + ((w * 512 + i * 64) << 4)),
            16, 0, 0);
    }
#else
    #pragma unroll
    for (int i = 0; i < 8; ++i) {
        int ci = w * 512 + i * 64 + l;
        *reinterpret_cast<uint4*>(&lds[ci << 4]) = reinterpret_cast<const uint4*>(zt_sw)[ci];
    }
#endif
    __syncthreads();

    // ---- X direct from global in MFMA A-layout: lane(m=l15) reads row's k-octets ----
    const int rowbase = blockIdx.x * 64 + w * 16;    // this wave's 16 rows
    const float* xrow = x + (size_t)(rowbase + l15) * D + (quad << 3);
    float4 xv[8];
    #pragma unroll
    for (int kc = 0; kc < 4; ++kc) {
        xv[2 * kc]     = *reinterpret_cast<const float4*>(xrow + (kc << 5));
        xv[2 * kc + 1] = *reinterpret_cast<const float4*>(xrow + (kc << 5) + 4);
    }

    // ---- ||x_row||^2 fp32 (pre-cast): lane partial + combine quads sharing l15 ----
    float ssq = 0.f;
    #pragma unroll
    for (int i = 0; i < 8; ++i)
        ssq += xv[i].x * xv[i].x + xv[i].y * xv[i].y + xv[i].z * xv[i].z + xv[i].w * xv[i].w;
    ssq += __shfl_xor(ssq, 16);
    ssq += __shfl_xor(ssq, 32);      // every lane: ssq of row (rowbase + l15)

    // ---- bf16 A-frags, 2.5 VALU/value bit-trick pack ----
    short8 afrag[4];
    #pragma unroll
    for (int kc = 0; kc < 4; ++kc) {
        union { short8 s8; unsigned u[4]; } af;
        af.u[0] = pack2(xv[2 * kc].x,     xv[2 * kc].y);
        af.u[1] = pack2(xv[2 * kc].z,     xv[2 * kc].w);
        af.u[2] = pack2(xv[2 * kc + 1].x, xv[2 * kc + 1].y);
        af.u[3] = pack2(xv[2 * kc + 1].z, xv[2 * kc + 1].w);
        afrag[kc] = af.s8;
    }

    // ---- MFMA 16x16x32 bf16, per-kc B preload (8 frags in regs -> ILP) ----
    floatx4 acc[8];
    #pragma unroll
    for (int nt = 0; nt < 8; ++nt) acc[nt] = (floatx4){0.f, 0.f, 0.f, 0.f};

    #pragma unroll
    for (int kc = 0; kc < 4; ++kc) {
        short8 b[8];
        #pragma unroll
        for (int nt = 0; nt < 8; ++nt)
            b[nt] = *reinterpret_cast<const short8*>(
                &lds[((nt * 16 + l15) << 8) + (((quad + (kc << 2)) ^ l7) << 4)]);
        #pragma unroll
        for (int nt = 0; nt < 8; ++nt)
            acc[nt] = __builtin_amdgcn_mfma_f32_16x16x32_bf16(afrag[kc], b[nt], acc[nt], 0, 0, 0);
    }

    // ---- epilogue: C/D layout col = lane&15, row = quad*4 + reg; direct scatter stores ----
    float4 cst[8];
    #pragma unroll
    for (int nt = 0; nt < 8; ++nt) cst[nt] = abs4[nt * 16 + l15];

    #pragma unroll
    for (int reg = 0; reg < 4; ++reg) {
        float rss = __shfl(ssq, (quad << 2) | reg);  // ssq of row quad*4+reg
        float lam = 2.0f / (1.0f - rss);
        float lm1 = lam - 1.0f;
        float* orow = out + (size_t)(rowbase + (quad << 2) + reg) * D + l15;
        #pragma unroll
        for (int nt = 0; nt < 8; ++nt) {
            float arg = __fmaf_rn(lam * acc[nt][reg], cst[nt].x, -lm1 * cst[nt].y);
            float a   = fabsf(arg);
            float as  = __log2f(a + __fsqrt_rn(__fmaf_rn(a, a, 1.0f)));  // asinh/ln2
            orow[nt * 16] = copysignf(as, arg) * cst[nt].z;              // cst.z = 2 zn ln2
        }
    }
}

extern "C" void kernel_launch(void* const* d_in, const int* in_sizes, int n_in,
                              void* d_out, int out_size, void* d_ws, size_t ws_size,
                              hipStream_t stream) {
    const float* x = (const float*)d_in[0];   // [16*8192, 128] fp32
    const float* z = (const float*)d_in[1];   // [128, 128] fp32
    const float* r = (const float*)d_in[2];   // [128] fp32
    float* out = (float*)d_out;

    // ws layout: zt_sw bf16 swizzled [128][128] (32768 B) | abs4 float4[128] (2048 B)
    char* wsb = (char*)d_ws;
    unsigned short* zt_sw = (unsigned short*)wsb;
    float4* abs4 = (float4*)(wsb + 128 * D * sizeof(unsigned short));

    hmlr_prep<<<128, 128, 0, stream>>>(z, r, zt_sw, abs4);

    const int n_rows = in_sizes[0] / D;       // 131072
    hmlr_main<<<n_rows / 64, 256, 0, stream>>>(x, zt_sw, abs4, out);
}